// Round 5
// baseline (144.357 us; speedup 1.0000x reference)
//
#include <hip/hip_runtime.h>
#include <hip/hip_bf16.h>

#define S_LEN 4096
#define DMODEL 512
#define NHEADS 8
#define HDIM 64

typedef __hip_bfloat16 bf16;
typedef __attribute__((ext_vector_type(8))) short bf16x8;
typedef __attribute__((ext_vector_type(4))) float f32x4;
typedef __attribute__((ext_vector_type(4))) _Float16 f16x4;
typedef __attribute__((ext_vector_type(8))) _Float16 f16x8;

__device__ __forceinline__ f32x4 mfma16x16x32(bf16x8 a, bf16x8 b, f32x4 c) {
    return __builtin_amdgcn_mfma_f32_16x16x32_bf16(a, b, c, 0, 0, 0);
}
__device__ __forceinline__ f32x4 mfma16x16x16h(f16x4 a, f16x4 b, f32x4 c) {
    return __builtin_amdgcn_mfma_f32_16x16x16f16(a, b, c, 0, 0, 0);
}
__device__ __forceinline__ f16x4 lo4(f16x8 v) { return __builtin_shufflevector(v, v, 0, 1, 2, 3); }
__device__ __forceinline__ f16x4 hi4(f16x8 v) { return __builtin_shufflevector(v, v, 4, 5, 6, 7); }
// async global->LDS, 16B per lane; LDS dest = wave-uniform base + lane*16,
// global source is PER-LANE.
__device__ __forceinline__ void gload_lds16(const void* g, void* l) {
    __builtin_amdgcn_global_load_lds(
        (const __attribute__((address_space(1))) unsigned int*)g,
        (__attribute__((address_space(3))) unsigned int*)l, 16, 0, 0);
}

// ---------------------------------------------------------------------------
// Prep: fused X fp32->bf16 convert (blocks 0..1023) and W transpose+convert
// (blocks 1024..2047).
// ---------------------------------------------------------------------------
__global__ __launch_bounds__(256) void prep(
    const float* __restrict__ X,
    const float* __restrict__ Wq, const float* __restrict__ Wk,
    const float* __restrict__ Wv, const float* __restrict__ Wo,
    bf16* __restrict__ Xb, bf16* __restrict__ Wt)
{
    __shared__ bf16 tile[32][33];
    const int b = blockIdx.x;
    if (b < 1024) {
        int i = (b * 256 + threadIdx.x) * 8;
        float4 a = *(const float4*)(X + i);
        float4 c = *(const float4*)(X + i + 4);
        bf16 tmp[8];
        tmp[0] = __float2bfloat16(a.x); tmp[1] = __float2bfloat16(a.y);
        tmp[2] = __float2bfloat16(a.z); tmp[3] = __float2bfloat16(a.w);
        tmp[4] = __float2bfloat16(c.x); tmp[5] = __float2bfloat16(c.y);
        tmp[6] = __float2bfloat16(c.z); tmp[7] = __float2bfloat16(c.w);
        *(bf16x8*)(Xb + i) = *(bf16x8*)tmp;
    } else {
        const int bb = b - 1024;
        const int z = bb >> 8;
        const int bx = bb & 15, by = (bb >> 4) & 15;
        const float* src = (z == 0) ? Wq : (z == 1) ? Wk : (z == 2) ? Wv : Wo;
        bf16* dst = Wt + (size_t)z * DMODEL * DMODEL;
        const int tx = threadIdx.x & 31, ty = threadIdx.x >> 5;
        const int x = bx * 32 + tx;
        const int y0 = by * 32;
        #pragma unroll
        for (int i = ty; i < 32; i += 8)
            tile[i][tx] = __float2bfloat16(src[(size_t)(y0 + i) * DMODEL + x]);
        __syncthreads();
        const int xo = y0 + tx;
        #pragma unroll
        for (int i = ty; i < 32; i += 8)
            dst[(size_t)(bx * 32 + i) * DMODEL + xo] = tile[tx][i];
    }
}

// ---------------------------------------------------------------------------
// Fused QKV projection: 64x64 tiles (grid 64x24 = 1536 blocks, ~5/CU),
// double-buffered LDS (32 KB), counted-vmcnt raw barriers (no mid-loop
// vmcnt(0) drain). Y = X[4096,512] @ Wt[1536,512]^T.
// n in [0,512)    -> Qm bf16, scaled (1/8)*log2(e)
// n in [512,1024) -> Km bf16
// n in [1024,1536)-> Vt  f16, transposed [512][4096], token-dim PERMUTED
//                    within each 64-block: pi(m) = ((m>>2)&3)*16+(m>>4)*4+(m&3)
//                    so attn reads V-frags as contiguous b128.
// ---------------------------------------------------------------------------
__global__ __launch_bounds__(256) void gemm_qkv(
    const bf16* __restrict__ A, const bf16* __restrict__ Bt,
    bf16* __restrict__ Qm, bf16* __restrict__ Km, _Float16* __restrict__ Vt)
{
    __shared__ __align__(16) bf16 As[2][64 * 64];
    __shared__ __align__(16) bf16 Bs[2][64 * 64];
    const int m0 = blockIdx.x * 64, n0 = blockIdx.y * 64;
    const int t = threadIdx.x, lane = t & 63, w = t >> 6;
    const int lr = lane & 15, lq = lane >> 4;

    f32x4 acc[4] = {f32x4{0,0,0,0}, f32x4{0,0,0,0}, f32x4{0,0,0,0}, f32x4{0,0,0,0}};

    // staging: wave w instr i covers rows w*8+i*32 .. +7; lane -> row +(lane>>3),
    // 16B chunk lane&7. LDS dest linear (1 KB contiguous per instr).
    const int srow = w * 8 + (lane >> 3);
    const int scol = (lane & 7) * 8;
    const bf16* Ab = A + (size_t)(m0 + srow) * DMODEL + scol;
    const bf16* Bb = Bt + (size_t)(n0 + srow) * DMODEL + scol;
    const int lb = (w * 8) * 64;

#define QKV_STAGE(k0, bsel) do {                                        \
        gload_lds16(Ab + (k0), &As[bsel][lb]);                          \
        gload_lds16(Ab + 32 * DMODEL + (k0), &As[bsel][lb + 32 * 64]);  \
        gload_lds16(Bb + (k0), &Bs[bsel][lb]);                          \
        gload_lds16(Bb + 32 * DMODEL + (k0), &Bs[bsel][lb + 32 * 64]);  \
    } while (0)

    QKV_STAGE(0, 0);
    #pragma unroll
    for (int ks = 0; ks < 8; ++ks) {
        const int cur = ks & 1;
        if (ks < 7) {
            QKV_STAGE((ks + 1) * 64, cur ^ 1);
            asm volatile("s_waitcnt vmcnt(4)" ::: "memory");   // tile ks landed
        } else {
            asm volatile("s_waitcnt vmcnt(0)" ::: "memory");
        }
        __builtin_amdgcn_s_barrier();
        __builtin_amdgcn_sched_barrier(0);
        #pragma unroll
        for (int kc = 0; kc < 2; ++kc) {
            bf16x8 a = *(const bf16x8*)&As[cur][(w * 16 + lr) * 64 + kc * 32 + lq * 8];
            #pragma unroll
            for (int nt = 0; nt < 4; ++nt) {
                bf16x8 b = *(const bf16x8*)&Bs[cur][(nt * 16 + lr) * 64 + kc * 32 + lq * 8];
                acc[nt] = mfma16x16x32(a, b, acc[nt]);
            }
        }
        asm volatile("s_waitcnt lgkmcnt(0)" ::: "memory");     // reads done before re-stage
        __builtin_amdgcn_sched_barrier(0);
        __builtin_amdgcn_s_barrier();
    }
#undef QKV_STAGE

    const int which = n0 >> 9;          // 0=Q 1=K 2=V
    const int nloc = n0 & 511;
    if (which == 0) {
        #pragma unroll
        for (int nt = 0; nt < 4; ++nt)
            #pragma unroll
            for (int r = 0; r < 4; ++r)
                Qm[(size_t)(m0 + w * 16 + lq * 4 + r) * DMODEL + nloc + nt * 16 + lr] =
                    __float2bfloat16(acc[nt][r] * 0.18033688f);   // (1/8)*log2e
    } else if (which == 1) {
        #pragma unroll
        for (int nt = 0; nt < 4; ++nt)
            #pragma unroll
            for (int r = 0; r < 4; ++r)
                Km[(size_t)(m0 + w * 16 + lq * 4 + r) * DMODEL + nloc + nt * 16 + lr] =
                    __float2bfloat16(acc[nt][r]);
    } else {
        // LDS transpose (reuse As; last loop barrier already synced) ->
        // permuted coalesced V^T stores
        _Float16* tb = (_Float16*)As;   // [64][72] f16
        #pragma unroll
        for (int nt = 0; nt < 4; ++nt)
            #pragma unroll
            for (int r = 0; r < 4; ++r)
                tb[(w * 16 + lq * 4 + r) * 72 + nt * 16 + lr] = (_Float16)acc[nt][r];
        __syncthreads();
        const int c = t >> 2, seg = t & 3;      // c: hd col 0..63, seg: 16-row chunk
        _Float16 tmp[16];
        #pragma unroll
        for (int j = 0; j < 16; ++j)
            tmp[j] = tb[(seg * 16 + j) * 72 + c];
        // m_local = seg*16+j  ->  pi = (j>>2)*16 + seg*4 + (j&3)
        _Float16* vp = Vt + (size_t)(nloc + c) * S_LEN + m0;
        #pragma unroll
        for (int g = 0; g < 4; ++g) {
            f16x4 vv = {tmp[g * 4 + 0], tmp[g * 4 + 1], tmp[g * 4 + 2], tmp[g * 4 + 3]};
            *(f16x4*)(vp + g * 16 + seg * 4) = vv;
        }
    }
}

// ---------------------------------------------------------------------------
// Out projection: 64x64 tiles (grid 64x8 = 512 blocks), same dbuf structure.
// out = AO[4096,512] @ Wot[512,512]^T + bias, fp32 out.
// ---------------------------------------------------------------------------
__global__ __launch_bounds__(256) void gemm_out(
    const bf16* __restrict__ A, const bf16* __restrict__ Bt,
    float* __restrict__ Out, const float* __restrict__ bias)
{
    __shared__ __align__(16) bf16 As[2][64 * 64];
    __shared__ __align__(16) bf16 Bs[2][64 * 64];
    const int m0 = blockIdx.x * 64, n0 = blockIdx.y * 64;
    const int t = threadIdx.x, lane = t & 63, w = t >> 6;
    const int lr = lane & 15, lq = lane >> 4;

    f32x4 acc[4] = {f32x4{0,0,0,0}, f32x4{0,0,0,0}, f32x4{0,0,0,0}, f32x4{0,0,0,0}};

    const int srow = w * 8 + (lane >> 3);
    const int scol = (lane & 7) * 8;
    const bf16* Ab = A + (size_t)(m0 + srow) * DMODEL + scol;
    const bf16* Bb = Bt + (size_t)(n0 + srow) * DMODEL + scol;
    const int lb = (w * 8) * 64;

#define OUT_STAGE(k0, bsel) do {                                        \
        gload_lds16(Ab + (k0), &As[bsel][lb]);                          \
        gload_lds16(Ab + 32 * DMODEL + (k0), &As[bsel][lb + 32 * 64]);  \
        gload_lds16(Bb + (k0), &Bs[bsel][lb]);                          \
        gload_lds16(Bb + 32 * DMODEL + (k0), &Bs[bsel][lb + 32 * 64]);  \
    } while (0)

    OUT_STAGE(0, 0);
    #pragma unroll
    for (int ks = 0; ks < 8; ++ks) {
        const int cur = ks & 1;
        if (ks < 7) {
            OUT_STAGE((ks + 1) * 64, cur ^ 1);
            asm volatile("s_waitcnt vmcnt(4)" ::: "memory");
        } else {
            asm volatile("s_waitcnt vmcnt(0)" ::: "memory");
        }
        __builtin_amdgcn_s_barrier();
        __builtin_amdgcn_sched_barrier(0);
        #pragma unroll
        for (int kc = 0; kc < 2; ++kc) {
            bf16x8 a = *(const bf16x8*)&As[cur][(w * 16 + lr) * 64 + kc * 32 + lq * 8];
            #pragma unroll
            for (int nt = 0; nt < 4; ++nt) {
                bf16x8 b = *(const bf16x8*)&Bs[cur][(nt * 16 + lr) * 64 + kc * 32 + lq * 8];
                acc[nt] = mfma16x16x32(a, b, acc[nt]);
            }
        }
        asm volatile("s_waitcnt lgkmcnt(0)" ::: "memory");
        __builtin_amdgcn_sched_barrier(0);
        __builtin_amdgcn_s_barrier();
    }
#undef OUT_STAGE

    #pragma unroll
    for (int nt = 0; nt < 4; ++nt)
        #pragma unroll
        for (int r = 0; r < 4; ++r)
            Out[(size_t)(m0 + w * 16 + lq * 4 + r) * DMODEL + n0 + nt * 16 + lr] =
                acc[nt][r] + bias[n0 + nt * 16 + lr];
}

// ---------------------------------------------------------------------------
// Attention v4: wave-decoupled kt-split, per-wave LDS staging (coalesced
// global_load_lds 16B, XOR-swizzle on global source + ds_read side).
// Changes vs v3:
//  - Vt token-permuted => V frags = 2x ds_read_b128 per ht (was 4x b64),
//    conflict-free (same pattern as K; v3's 2^21 conflicts were V b64 parity).
//  - row-sum lsum via ones-vector MFMA (matrix pipe) instead of 64 VALU adds.
// grid (H, S/64): block id % 8 == head -> per-XCD L2-resident K/V.
// ---------------------------------------------------------------------------
__global__ __launch_bounds__(256, 2) void attn_kernel(
    const bf16* __restrict__ Q, const bf16* __restrict__ Kmat,
    const _Float16* __restrict__ Vt, bf16* __restrict__ Oout)
{
    __shared__ __align__(16) char smem[65536];  // 4 waves x (8KB K + 8KB V); epilogue aliases

    const int h = blockIdx.x, qb = blockIdx.y;
    const int t = threadIdx.x, lane = t & 63, w = t >> 6;
    const int lr = lane & 15, lq = lane >> 4;
    const int q0 = qb * 64;

    char* myK = smem + w * 16384;       // [64 rows][128B]  K tile (bf16)
    char* myV = myK + 8192;             // [64 hd  ][128B]  V^T tile (f16, token-permuted)

    const int sr = lane >> 3;
    const int scc = (lane & 7) ^ sr;                 // pre-swizzled global chunk
    const bf16*     gK = Kmat + (size_t)sr * DMODEL + h * HDIM + scc * 8;
    const _Float16* gV = Vt + (size_t)(h * HDIM + sr) * S_LEN + scc * 8;

    // Q B-frags for all 4 qt tiles
    bf16x8 qf[4][2];
    #pragma unroll
    for (int qt = 0; qt < 4; ++qt) {
        const bf16* qp = Q + (size_t)(q0 + qt * 16 + lr) * DMODEL + h * HDIM + lq * 8;
        qf[qt][0] = *(const bf16x8*)qp;
        qf[qt][1] = *(const bf16x8*)(qp + 32);
    }

    f32x4 oacc[4][4];   // [qt][ht]; C: row(Q)=lq*4+r, col(hd)=lr
    #pragma unroll
    for (int i = 0; i < 4; ++i)
        #pragma unroll
        for (int j = 0; j < 4; ++j) oacc[i][j] = f32x4{0, 0, 0, 0};
    f32x4 lacc[4];      // [qt]; row-sum via ones-MFMA: row(Q)=lq*4+r, all cols equal
    #pragma unroll
    for (int i = 0; i < 4; ++i) lacc[i] = f32x4{0, 0, 0, 0};
    const f16x4 vones = {(_Float16)1.0f, (_Float16)1.0f, (_Float16)1.0f, (_Float16)1.0f};

    // prologue: stage first tile (kt = w)
    #pragma unroll
    for (int i = 0; i < 8; ++i) {
        gload_lds16(gK + (size_t)(w * 64 + i * 8) * DMODEL, myK + i * 1024);
        gload_lds16(gV + (size_t)(i * 8) * S_LEN + w * 64, myV + i * 1024);
    }

    const int swz = (lr & 7) << 4;

    for (int kt = w; kt < S_LEN / 64; kt += 4) {
        asm volatile("s_waitcnt vmcnt(0)" ::: "memory");  // staged tile landed

        // K frags (swizzled ds_read_b128, conflict-free)
        bf16x8 kf[4][2];
        #pragma unroll
        for (int mt = 0; mt < 4; ++mt) {
            const char* kr = myK + (mt * 16 + lr) * 128;
            kf[mt][0] = *(const bf16x8*)(kr + ((lq * 16) ^ swz));
            kf[mt][1] = *(const bf16x8*)(kr + ((64 + lq * 16) ^ swz));
        }
        // V frags: token-permuted layout -> lane's 4 x 8B are contiguous 32B
        // = 2 swizzled b128 per ht (same conflict-free pattern as K)
        f16x8 vA[4], vB[4];   // [ht]: vA = mt 0,1 ; vB = mt 2,3
        #pragma unroll
        for (int ht = 0; ht < 4; ++ht) {
            const char* vr = myV + (ht * 16 + lr) * 128;
            vA[ht] = *(const f16x8*)(vr + ((lq * 32) ^ swz));
            vB[ht] = *(const f16x8*)(vr + ((lq * 32 + 16) ^ swz));
        }
        asm volatile("s_waitcnt lgkmcnt(0)" ::: "memory");
        __builtin_amdgcn_sched_barrier(0);

        // issue-early prefetch of next tile (overlaps with compute below)
        const int ktn = kt + 4;
        if (ktn < S_LEN / 64) {
            #pragma unroll
            for (int i = 0; i < 8; ++i) {
                gload_lds16(gK + (size_t)(ktn * 64 + i * 8) * DMODEL, myK + i * 1024);
                gload_lds16(gV + (size_t)(i * 8) * S_LEN + ktn * 64, myV + i * 1024);
            }
        }

        __builtin_amdgcn_s_setprio(1);
        // S^T = K @ Q^T ; P = exp2(S^T)  (log2e folded into Q)
        f16x4 pf[4][4];   // [qt][mt]
        #pragma unroll
        for (int qt = 0; qt < 4; ++qt) {
            f32x4 st[4];
            #pragma unroll
            for (int mt = 0; mt < 4; ++mt) {
                f32x4 z = {0, 0, 0, 0};
                z = mfma16x16x32(kf[mt][0], qf[qt][0], z);
                z = mfma16x16x32(kf[mt][1], qf[qt][1], z);
                st[mt] = z;
            }
            #pragma unroll
            for (int mt = 0; mt < 4; ++mt)
                #pragma unroll
                for (int r = 0; r < 4; ++r)
                    pf[qt][mt][r] = (_Float16)__builtin_amdgcn_exp2f(st[mt][r]);
        }
        // O += P @ V
        #pragma unroll
        for (int qt = 0; qt < 4; ++qt)
            #pragma unroll
            for (int ht = 0; ht < 4; ++ht) {
                oacc[qt][ht] = mfma16x16x16h(pf[qt][0], lo4(vA[ht]), oacc[qt][ht]);
                oacc[qt][ht] = mfma16x16x16h(pf[qt][1], hi4(vA[ht]), oacc[qt][ht]);
                oacc[qt][ht] = mfma16x16x16h(pf[qt][2], lo4(vB[ht]), oacc[qt][ht]);
                oacc[qt][ht] = mfma16x16x16h(pf[qt][3], hi4(vB[ht]), oacc[qt][ht]);
            }
        // row sums on the matrix pipe: lacc[qt][r] = sum_k P[q=lq*4+r][k]
        #pragma unroll
        for (int qt = 0; qt < 4; ++qt)
            #pragma unroll
            for (int mt = 0; mt < 4; ++mt)
                lacc[qt] = mfma16x16x16h(pf[qt][mt], vones, lacc[qt]);
        __builtin_amdgcn_s_setprio(0);
    }

    // ---- cross-wave combine; obuf ALIASES the staging LDS ----
    __syncthreads();
    float (*obuf)[3][4][64][4] = (float(*)[3][4][64][4])smem;   // 48KB
    float (*lbuf)[4][16]       = (float(*)[4][16])(smem + 49152);

    #pragma unroll
    for (int qt = 0; qt < 4; ++qt) {
        if (qt != w) {
            int j = qt - (qt > w ? 1 : 0);
            #pragma unroll
            for (int ht = 0; ht < 4; ++ht)
                *(f32x4*)&obuf[w][j][ht][lane][0] = oacc[qt][ht];
        }
    }
    // publish row sums (all cols of lacc identical; lanes with lr==0 write)
    if (lr == 0) {
        #pragma unroll
        for (int qt = 0; qt < 4; ++qt)
            #pragma unroll
            for (int r = 0; r < 4; ++r)
                lbuf[w][qt][lq * 4 + r] = lacc[qt][r];
    }
    __syncthreads();

    // wave w finalizes qt == w
    f32x4 osum[4];
    #pragma unroll
    for (int qt = 0; qt < 4; ++qt)
        if (qt == w) {
            #pragma unroll
            for (int ht = 0; ht < 4; ++ht) osum[ht] = oacc[qt][ht];
        }
    #pragma unroll
    for (int w2 = 0; w2 < 4; ++w2) {
        if (w2 == w) continue;
        int j = w - (w > w2 ? 1 : 0);
        #pragma unroll
        for (int ht = 0; ht < 4; ++ht)
            osum[ht] += *(const f32x4*)&obuf[w2][j][ht][lane][0];
    }
    float linv[4];
    #pragma unroll
    for (int r = 0; r < 4; ++r) {
        int rr = lq * 4 + r;
        linv[r] = 1.0f / (lbuf[0][w][rr] + lbuf[1][w][rr] + lbuf[2][w][rr] + lbuf[3][w][rr]);
    }
    #pragma unroll
    for (int r = 0; r < 4; ++r) {
        int row = q0 + w * 16 + lq * 4 + r;
        #pragma unroll
        for (int ht = 0; ht < 4; ++ht)
            Oout[(size_t)row * DMODEL + h * HDIM + ht * 16 + lr] =
                __float2bfloat16(osum[ht][r] * linv[r]);
    }
}

// ---------------------------------------------------------------------------
extern "C" void kernel_launch(void* const* d_in, const int* in_sizes, int n_in,
                              void* d_out, int out_size, void* d_ws, size_t ws_size,
                              hipStream_t stream) {
    const float* X  = (const float*)d_in[0];
    const float* Wq = (const float*)d_in[1];
    const float* Wk = (const float*)d_in[2];
    const float* Wv = (const float*)d_in[3];
    const float* Wo = (const float*)d_in[4];
    const float* bo = (const float*)d_in[5];
    float* out = (float*)d_out;

    char* ws = (char*)d_ws;
    bf16* Wt = (bf16*)ws;                                  // [4][512][512] bf16
    bf16* Xb = (bf16*)(ws + (size_t)4 * DMODEL * DMODEL * 2);
    bf16* Qm = Xb + (size_t)S_LEN * DMODEL;
    bf16* Km = Qm + (size_t)S_LEN * DMODEL;
    _Float16* Vt = (_Float16*)(Km + (size_t)S_LEN * DMODEL);   // [512][4096] f16 (permuted)
    bf16* AO = (bf16*)(Vt + (size_t)S_LEN * DMODEL);

    bf16* Wot = Wt + (size_t)3 * DMODEL * DMODEL;

    prep<<<2048, 256, 0, stream>>>(X, Wq, Wk, Wv, Wo, Xb, Wt);

    gemm_qkv<<<dim3(S_LEN / 64, 3 * DMODEL / 64), 256, 0, stream>>>(
        Xb, Wt, Qm, Km, Vt);

    attn_kernel<<<dim3(NHEADS, S_LEN / 64), 256, 0, stream>>>(Qm, Km, Vt, AO);

    gemm_out<<<dim3(S_LEN / 64, DMODEL / 64), 256, 0, stream>>>(AO, Wot, out, bo);
}

// Round 8
// 134.735 us; speedup vs baseline: 1.0714x; 1.0714x over previous
//
#include <hip/hip_runtime.h>
#include <hip/hip_bf16.h>

#define S_LEN 4096
#define DMODEL 512
#define NHEADS 8
#define HDIM 64

typedef __hip_bfloat16 bf16;
typedef __attribute__((ext_vector_type(8))) short bf16x8;
typedef __attribute__((ext_vector_type(4))) float f32x4;
typedef __attribute__((ext_vector_type(4))) _Float16 f16x4;
typedef __attribute__((ext_vector_type(8))) _Float16 f16x8;

__device__ __forceinline__ f32x4 mfma16x16x32(bf16x8 a, bf16x8 b, f32x4 c) {
    return __builtin_amdgcn_mfma_f32_16x16x32_bf16(a, b, c, 0, 0, 0);
}
__device__ __forceinline__ f32x4 mfma16x16x16h(f16x4 a, f16x4 b, f32x4 c) {
    return __builtin_amdgcn_mfma_f32_16x16x16f16(a, b, c, 0, 0, 0);
}
__device__ __forceinline__ f16x4 lo4(f16x8 v) { return __builtin_shufflevector(v, v, 0, 1, 2, 3); }
__device__ __forceinline__ f16x4 hi4(f16x8 v) { return __builtin_shufflevector(v, v, 4, 5, 6, 7); }
// async global->LDS, 16B per lane; LDS dest = wave-uniform base + lane*16,
// global source is PER-LANE (pre-swizzle source for swizzled LDS layouts).
__device__ __forceinline__ void gload_lds16(const void* g, void* l) {
    __builtin_amdgcn_global_load_lds(
        (const __attribute__((address_space(1))) unsigned int*)g,
        (__attribute__((address_space(3))) unsigned int*)l, 16, 0, 0);
}

// ---------------------------------------------------------------------------
// Prep: fused X fp32->bf16 convert (blocks 0..1023) and W transpose+convert
// (blocks 1024..2047).
// ---------------------------------------------------------------------------
__global__ __launch_bounds__(256) void prep(
    const float* __restrict__ X,
    const float* __restrict__ Wq, const float* __restrict__ Wk,
    const float* __restrict__ Wv, const float* __restrict__ Wo,
    bf16* __restrict__ Xb, bf16* __restrict__ Wt)
{
    __shared__ bf16 tile[32][33];
    const int b = blockIdx.x;
    if (b < 1024) {
        int i = (b * 256 + threadIdx.x) * 8;
        float4 a = *(const float4*)(X + i);
        float4 c = *(const float4*)(X + i + 4);
        bf16 tmp[8];
        tmp[0] = __float2bfloat16(a.x); tmp[1] = __float2bfloat16(a.y);
        tmp[2] = __float2bfloat16(a.z); tmp[3] = __float2bfloat16(a.w);
        tmp[4] = __float2bfloat16(c.x); tmp[5] = __float2bfloat16(c.y);
        tmp[6] = __float2bfloat16(c.z); tmp[7] = __float2bfloat16(c.w);
        *(bf16x8*)(Xb + i) = *(bf16x8*)tmp;
    } else {
        const int bb = b - 1024;
        const int z = bb >> 8;
        const int bx = bb & 15, by = (bb >> 4) & 15;
        const float* src = (z == 0) ? Wq : (z == 1) ? Wk : (z == 2) ? Wv : Wo;
        bf16* dst = Wt + (size_t)z * DMODEL * DMODEL;
        const int tx = threadIdx.x & 31, ty = threadIdx.x >> 5;
        const int x = bx * 32 + tx;
        const int y0 = by * 32;
        #pragma unroll
        for (int i = ty; i < 32; i += 8)
            tile[i][tx] = __float2bfloat16(src[(size_t)(y0 + i) * DMODEL + x]);
        __syncthreads();
        const int xo = y0 + tx;
        #pragma unroll
        for (int i = ty; i < 32; i += 8)
            dst[(size_t)(bx * 32 + i) * DMODEL + xo] = tile[tx][i];
    }
}

// ---------------------------------------------------------------------------
// Fused QKV projection: 64x64 tiles (grid 64x24 = 1536 blocks, ~5/CU),
// double-buffered LDS, counted-vmcnt raw barriers, T2 XOR-SWIZZLED LDS
// (both-sides involution: pre-swizzled global source chunk, swizzled read;
// removes the 16-way fragment-read bank conflict of the linear layout).
// Y = X[4096,512] @ Wt[1536,512]^T.
// n in [0,512)    -> Qm bf16, scaled (1/8)*log2(e)
// n in [512,1024) -> Km bf16
// n in [1024,1536)-> Vt  f16, transposed [512][4096], token-dim PERMUTED
//                    within each 64-block: pi(m)=((m>>2)&3)*16+(m>>4)*4+(m&3)
// ---------------------------------------------------------------------------
__global__ __launch_bounds__(256) void gemm_qkv(
    const bf16* __restrict__ A, const bf16* __restrict__ Bt,
    bf16* __restrict__ Qm, bf16* __restrict__ Km, _Float16* __restrict__ Vt)
{
    __shared__ __align__(16) bf16 As[2][64 * 64];
    __shared__ __align__(16) bf16 Bs[2][64 * 64];
    const int m0 = blockIdx.x * 64, n0 = blockIdx.y * 64;
    const int t = threadIdx.x, lane = t & 63, w = t >> 6;
    const int lr = lane & 15, lq = lane >> 4;
    const int swz = (lr & 7) << 4;

    f32x4 acc[4] = {f32x4{0,0,0,0}, f32x4{0,0,0,0}, f32x4{0,0,0,0}, f32x4{0,0,0,0}};

    // staging: wave w instr i covers rows w*8+i*32 .. +7; lane -> row +(lane>>3),
    // 16B chunk ((lane&7) ^ (lane>>3)) -- pre-swizzled global source, linear LDS.
    const int srow = w * 8 + (lane >> 3);
    const int scol = ((lane & 7) ^ (lane >> 3)) * 8;
    const bf16* Ab = A + (size_t)(m0 + srow) * DMODEL + scol;
    const bf16* Bb = Bt + (size_t)(n0 + srow) * DMODEL + scol;
    const int lb = (w * 8) * 64;

#define QKV_STAGE(k0, bsel) do {                                        \
        gload_lds16(Ab + (k0), &As[bsel][lb]);                          \
        gload_lds16(Ab + 32 * DMODEL + (k0), &As[bsel][lb + 32 * 64]);  \
        gload_lds16(Bb + (k0), &Bs[bsel][lb]);                          \
        gload_lds16(Bb + 32 * DMODEL + (k0), &Bs[bsel][lb + 32 * 64]);  \
    } while (0)

    QKV_STAGE(0, 0);
    #pragma unroll
    for (int ks = 0; ks < 8; ++ks) {
        const int cur = ks & 1;
        if (ks < 7) {
            QKV_STAGE((ks + 1) * 64, cur ^ 1);
            asm volatile("s_waitcnt vmcnt(4)" ::: "memory");   // tile ks landed
        } else {
            asm volatile("s_waitcnt vmcnt(0)" ::: "memory");
        }
        __builtin_amdgcn_s_barrier();
        __builtin_amdgcn_sched_barrier(0);
        const char* Ab8 = (const char*)&As[cur][0];
        const char* Bb8 = (const char*)&Bs[cur][0];
        #pragma unroll
        for (int kc = 0; kc < 2; ++kc) {
            bf16x8 a = *(const bf16x8*)(Ab8 + (w * 16 + lr) * 128 + ((kc * 64 + lq * 16) ^ swz));
            #pragma unroll
            for (int nt = 0; nt < 4; ++nt) {
                bf16x8 b = *(const bf16x8*)(Bb8 + (nt * 16 + lr) * 128 + ((kc * 64 + lq * 16) ^ swz));
                acc[nt] = mfma16x16x32(a, b, acc[nt]);
            }
        }
        asm volatile("s_waitcnt lgkmcnt(0)" ::: "memory");     // reads done before re-stage
        __builtin_amdgcn_sched_barrier(0);
        __builtin_amdgcn_s_barrier();
    }
#undef QKV_STAGE

    const int which = n0 >> 9;          // 0=Q 1=K 2=V
    const int nloc = n0 & 511;
    if (which == 0) {
        #pragma unroll
        for (int nt = 0; nt < 4; ++nt)
            #pragma unroll
            for (int r = 0; r < 4; ++r)
                Qm[(size_t)(m0 + w * 16 + lq * 4 + r) * DMODEL + nloc + nt * 16 + lr] =
                    __float2bfloat16(acc[nt][r] * 0.18033688f);   // (1/8)*log2e
    } else if (which == 1) {
        #pragma unroll
        for (int nt = 0; nt < 4; ++nt)
            #pragma unroll
            for (int r = 0; r < 4; ++r)
                Km[(size_t)(m0 + w * 16 + lq * 4 + r) * DMODEL + nloc + nt * 16 + lr] =
                    __float2bfloat16(acc[nt][r]);
    } else {
        // LDS transpose (reuse As; last loop barrier already synced) ->
        // permuted coalesced V^T stores
        _Float16* tb = (_Float16*)As;   // [64][72] f16
        #pragma unroll
        for (int nt = 0; nt < 4; ++nt)
            #pragma unroll
            for (int r = 0; r < 4; ++r)
                tb[(w * 16 + lq * 4 + r) * 72 + nt * 16 + lr] = (_Float16)acc[nt][r];
        __syncthreads();
        const int c = t >> 2, seg = t & 3;      // c: hd col 0..63, seg: 16-row chunk
        _Float16 tmp[16];
        #pragma unroll
        for (int j = 0; j < 16; ++j)
            tmp[j] = tb[(seg * 16 + j) * 72 + c];
        // m_local = seg*16+j  ->  pi = (j>>2)*16 + seg*4 + (j&3)
        _Float16* vp = Vt + (size_t)(nloc + c) * S_LEN + m0;
        #pragma unroll
        for (int g = 0; g < 4; ++g) {
            f16x4 vv = {tmp[g * 4 + 0], tmp[g * 4 + 1], tmp[g * 4 + 2], tmp[g * 4 + 3]};
            *(f16x4*)(vp + g * 16 + seg * 4) = vv;
        }
    }
}

// ---------------------------------------------------------------------------
// Out projection: 64x64 tiles (grid 64x8 = 512 blocks), same dbuf + swizzle.
// out = AO[4096,512] @ Wot[512,512]^T + bias, fp32 out.
// ---------------------------------------------------------------------------
__global__ __launch_bounds__(256) void gemm_out(
    const bf16* __restrict__ A, const bf16* __restrict__ Bt,
    float* __restrict__ Out, const float* __restrict__ bias)
{
    __shared__ __align__(16) bf16 As[2][64 * 64];
    __shared__ __align__(16) bf16 Bs[2][64 * 64];
    const int m0 = blockIdx.x * 64, n0 = blockIdx.y * 64;
    const int t = threadIdx.x, lane = t & 63, w = t >> 6;
    const int lr = lane & 15, lq = lane >> 4;
    const int swz = (lr & 7) << 4;

    f32x4 acc[4] = {f32x4{0,0,0,0}, f32x4{0,0,0,0}, f32x4{0,0,0,0}, f32x4{0,0,0,0}};

    const int srow = w * 8 + (lane >> 3);
    const int scol = ((lane & 7) ^ (lane >> 3)) * 8;
    const bf16* Ab = A + (size_t)(m0 + srow) * DMODEL + scol;
    const bf16* Bb = Bt + (size_t)(n0 + srow) * DMODEL + scol;
    const int lb = (w * 8) * 64;

#define OUT_STAGE(k0, bsel) do {                                        \
        gload_lds16(Ab + (k0), &As[bsel][lb]);                          \
        gload_lds16(Ab + 32 * DMODEL + (k0), &As[bsel][lb + 32 * 64]);  \
        gload_lds16(Bb + (k0), &Bs[bsel][lb]);                          \
        gload_lds16(Bb + 32 * DMODEL + (k0), &Bs[bsel][lb + 32 * 64]);  \
    } while (0)

    OUT_STAGE(0, 0);
    #pragma unroll
    for (int ks = 0; ks < 8; ++ks) {
        const int cur = ks & 1;
        if (ks < 7) {
            OUT_STAGE((ks + 1) * 64, cur ^ 1);
            asm volatile("s_waitcnt vmcnt(4)" ::: "memory");
        } else {
            asm volatile("s_waitcnt vmcnt(0)" ::: "memory");
        }
        __builtin_amdgcn_s_barrier();
        __builtin_amdgcn_sched_barrier(0);
        const char* Ab8 = (const char*)&As[cur][0];
        const char* Bb8 = (const char*)&Bs[cur][0];
        #pragma unroll
        for (int kc = 0; kc < 2; ++kc) {
            bf16x8 a = *(const bf16x8*)(Ab8 + (w * 16 + lr) * 128 + ((kc * 64 + lq * 16) ^ swz));
            #pragma unroll
            for (int nt = 0; nt < 4; ++nt) {
                bf16x8 b = *(const bf16x8*)(Bb8 + (nt * 16 + lr) * 128 + ((kc * 64 + lq * 16) ^ swz));
                acc[nt] = mfma16x16x32(a, b, acc[nt]);
            }
        }
        asm volatile("s_waitcnt lgkmcnt(0)" ::: "memory");
        __builtin_amdgcn_sched_barrier(0);
        __builtin_amdgcn_s_barrier();
    }
#undef OUT_STAGE

    #pragma unroll
    for (int nt = 0; nt < 4; ++nt)
        #pragma unroll
        for (int r = 0; r < 4; ++r)
            Out[(size_t)(m0 + w * 16 + lq * 4 + r) * DMODEL + n0 + nt * 16 + lr] =
                acc[nt][r] + bias[n0 + nt * 16 + lr];
}

// ---------------------------------------------------------------------------
// Attention v5: wave-decoupled kt-split, per-wave LDS staging (coalesced
// global_load_lds 16B, XOR-swizzle on global source + ds_read side).
// = round-3 structure (VALU lsum) + round-5 b128 permuted-V reads.
// (r5's ones-MFMA row-sum was a measured regression: MfmaUtil +7 for
//  VALUBusy -4, net -5% -- reverted.)
// grid (H, S/64): block id % 8 == head -> per-XCD L2-resident K/V.
// ---------------------------------------------------------------------------
__global__ __launch_bounds__(256, 2) void attn_kernel(
    const bf16* __restrict__ Q, const bf16* __restrict__ Kmat,
    const _Float16* __restrict__ Vt, bf16* __restrict__ Oout)
{
    __shared__ __align__(16) char smem[65536];  // 4 waves x (8KB K + 8KB V); epilogue aliases

    const int h = blockIdx.x, qb = blockIdx.y;
    const int t = threadIdx.x, lane = t & 63, w = t >> 6;
    const int lr = lane & 15, lq = lane >> 4;
    const int q0 = qb * 64;

    char* myK = smem + w * 16384;       // [64 rows][128B]  K tile (bf16)
    char* myV = myK + 8192;             // [64 hd  ][128B]  V^T tile (f16, token-permuted)

    const int sr = lane >> 3;
    const int scc = (lane & 7) ^ sr;                 // pre-swizzled global chunk
    const bf16*     gK = Kmat + (size_t)sr * DMODEL + h * HDIM + scc * 8;
    const _Float16* gV = Vt + (size_t)(h * HDIM + sr) * S_LEN + scc * 8;

    // Q B-frags for all 4 qt tiles
    bf16x8 qf[4][2];
    #pragma unroll
    for (int qt = 0; qt < 4; ++qt) {
        const bf16* qp = Q + (size_t)(q0 + qt * 16 + lr) * DMODEL + h * HDIM + lq * 8;
        qf[qt][0] = *(const bf16x8*)qp;
        qf[qt][1] = *(const bf16x8*)(qp + 32);
    }

    f32x4 oacc[4][4];   // [qt][ht]; C: row(Q)=lq*4+r, col(hd)=lr
    #pragma unroll
    for (int i = 0; i < 4; ++i)
        #pragma unroll
        for (int j = 0; j < 4; ++j) oacc[i][j] = f32x4{0, 0, 0, 0};
    float lsum[4] = {0, 0, 0, 0};

    // prologue: stage first tile (kt = w)
    #pragma unroll
    for (int i = 0; i < 8; ++i) {
        gload_lds16(gK + (size_t)(w * 64 + i * 8) * DMODEL, myK + i * 1024);
        gload_lds16(gV + (size_t)(i * 8) * S_LEN + w * 64, myV + i * 1024);
    }

    const int swz = (lr & 7) << 4;

    for (int kt = w; kt < S_LEN / 64; kt += 4) {
        asm volatile("s_waitcnt vmcnt(0)" ::: "memory");  // staged tile landed

        // K frags (swizzled ds_read_b128, 2-way max)
        bf16x8 kf[4][2];
        #pragma unroll
        for (int mt = 0; mt < 4; ++mt) {
            const char* kr = myK + (mt * 16 + lr) * 128;
            kf[mt][0] = *(const bf16x8*)(kr + ((lq * 16) ^ swz));
            kf[mt][1] = *(const bf16x8*)(kr + ((64 + lq * 16) ^ swz));
        }
        // V frags: token-permuted layout -> lane's 4 x 8B are contiguous 32B
        // = 2 swizzled b128 per ht (same pattern as K)
        f16x8 vA[4], vB[4];   // [ht]: vA = mt 0,1 ; vB = mt 2,3
        #pragma unroll
        for (int ht = 0; ht < 4; ++ht) {
            const char* vr = myV + (ht * 16 + lr) * 128;
            vA[ht] = *(const f16x8*)(vr + ((lq * 32) ^ swz));
            vB[ht] = *(const f16x8*)(vr + ((lq * 32 + 16) ^ swz));
        }
        asm volatile("s_waitcnt lgkmcnt(0)" ::: "memory");
        __builtin_amdgcn_sched_barrier(0);

        // issue-early prefetch of next tile (overlaps with compute below)
        const int ktn = kt + 4;
        if (ktn < S_LEN / 64) {
            #pragma unroll
            for (int i = 0; i < 8; ++i) {
                gload_lds16(gK + (size_t)(ktn * 64 + i * 8) * DMODEL, myK + i * 1024);
                gload_lds16(gV + (size_t)(i * 8) * S_LEN + ktn * 64, myV + i * 1024);
            }
        }

        __builtin_amdgcn_s_setprio(1);
        // S^T = K @ Q^T ; P = exp2(S^T)  (log2e folded into Q)
        f16x4 pf[4][4];   // [qt][mt]
        #pragma unroll
        for (int qt = 0; qt < 4; ++qt) {
            f32x4 st[4];
            #pragma unroll
            for (int mt = 0; mt < 4; ++mt) {
                f32x4 z = {0, 0, 0, 0};
                z = mfma16x16x32(kf[mt][0], qf[qt][0], z);
                z = mfma16x16x32(kf[mt][1], qf[qt][1], z);
                st[mt] = z;
            }
            #pragma unroll
            for (int mt = 0; mt < 4; ++mt)
                #pragma unroll
                for (int r = 0; r < 4; ++r) {
                    float p = __builtin_amdgcn_exp2f(st[mt][r]);
                    lsum[qt] += p;
                    pf[qt][mt][r] = (_Float16)p;
                }
        }
        // O += P @ V
        #pragma unroll
        for (int qt = 0; qt < 4; ++qt)
            #pragma unroll
            for (int ht = 0; ht < 4; ++ht) {
                oacc[qt][ht] = mfma16x16x16h(pf[qt][0], lo4(vA[ht]), oacc[qt][ht]);
                oacc[qt][ht] = mfma16x16x16h(pf[qt][1], hi4(vA[ht]), oacc[qt][ht]);
                oacc[qt][ht] = mfma16x16x16h(pf[qt][2], lo4(vB[ht]), oacc[qt][ht]);
                oacc[qt][ht] = mfma16x16x16h(pf[qt][3], hi4(vB[ht]), oacc[qt][ht]);
            }
        __builtin_amdgcn_s_setprio(0);
    }

    // ---- cross-wave combine; obuf ALIASES the staging LDS ----
    __syncthreads();
    float (*obuf)[3][4][64][4] = (float(*)[3][4][64][4])smem;   // 48KB
    float (*lbuf)[4][16]       = (float(*)[4][16])(smem + 49152);

    #pragma unroll
    for (int qt = 0; qt < 4; ++qt) {
        if (qt != w) {
            int j = qt - (qt > w ? 1 : 0);
            #pragma unroll
            for (int ht = 0; ht < 4; ++ht)
                *(f32x4*)&obuf[w][j][ht][lane][0] = oacc[qt][ht];
        }
    }
    // row sums: reduce over lq groups, publish
    #pragma unroll
    for (int qt = 0; qt < 4; ++qt) {
        float s = lsum[qt];
        s += __shfl_xor(s, 16);
        s += __shfl_xor(s, 32);
        if (lq == 0) lbuf[w][qt][lr] = s;
    }
    __syncthreads();

    // wave w finalizes qt == w
    f32x4 osum[4];
    #pragma unroll
    for (int qt = 0; qt < 4; ++qt)
        if (qt == w) {
            #pragma unroll
            for (int ht = 0; ht < 4; ++ht) osum[ht] = oacc[qt][ht];
        }
    #pragma unroll
    for (int w2 = 0; w2 < 4; ++w2) {
        if (w2 == w) continue;
        int j = w - (w > w2 ? 1 : 0);
        #pragma unroll
        for (int ht = 0; ht < 4; ++ht)
            osum[ht] += *(const f32x4*)&obuf[w2][j][ht][lane][0];
    }
    float linv[4];
    #pragma unroll
    for (int r = 0; r < 4; ++r) {
        int rr = lq * 4 + r;
        linv[r] = 1.0f / (lbuf[0][w][rr] + lbuf[1][w][rr] + lbuf[2][w][rr] + lbuf[3][w][rr]);
    }
    #pragma unroll
    for (int r = 0; r < 4; ++r) {
        int row = q0 + w * 16 + lq * 4 + r;
        #pragma unroll
        for (int ht = 0; ht < 4; ++ht)
            Oout[(size_t)row * DMODEL + h * HDIM + ht * 16 + lr] =
                __float2bfloat16(osum[ht][r] * linv[r]);
    }
}

// ---------------------------------------------------------------------------
extern "C" void kernel_launch(void* const* d_in, const int* in_sizes, int n_in,
                              void* d_out, int out_size, void* d_ws, size_t ws_size,
                              hipStream_t stream) {
    const float* X  = (const float*)d_in[0];
    const float* Wq = (const float*)d_in[1];
    const float* Wk = (const float*)d_in[2];
    const float* Wv = (const float*)d_in[3];
    const float* Wo = (const float*)d_in[4];
    const float* bo = (const float*)d_in[5];
    float* out = (float*)d_out;

    char* ws = (char*)d_ws;
    bf16* Wt = (bf16*)ws;                                  // [4][512][512] bf16
    bf16* Xb = (bf16*)(ws + (size_t)4 * DMODEL * DMODEL * 2);
    bf16* Qm = Xb + (size_t)S_LEN * DMODEL;
    bf16* Km = Qm + (size_t)S_LEN * DMODEL;
    _Float16* Vt = (_Float16*)(Km + (size_t)S_LEN * DMODEL);   // [512][4096] f16 (permuted)
    bf16* AO = (bf16*)(Vt + (size_t)S_LEN * DMODEL);

    bf16* Wot = Wt + (size_t)3 * DMODEL * DMODEL;

    prep<<<2048, 256, 0, stream>>>(X, Wq, Wk, Wv, Wo, Xb, Wt);

    gemm_qkv<<<dim3(S_LEN / 64, 3 * DMODEL / 64), 256, 0, stream>>>(
        Xb, Wt, Qm, Km, Vt);

    attn_kernel<<<dim3(NHEADS, S_LEN / 64), 256, 0, stream>>>(Qm, Km, Vt, AO);

    gemm_out<<<dim3(S_LEN / 64, DMODEL / 64), 256, 0, stream>>>(AO, Wot, out, bo);
}

// Round 10
// 128.251 us; speedup vs baseline: 1.1256x; 1.0506x over previous
//
#include <hip/hip_runtime.h>
#include <hip/hip_bf16.h>

#define S_LEN 4096
#define DMODEL 512
#define NHEADS 8
#define HDIM 64

typedef __hip_bfloat16 bf16;
typedef __attribute__((ext_vector_type(8))) short bf16x8;
typedef __attribute__((ext_vector_type(4))) float f32x4;
typedef __attribute__((ext_vector_type(2))) _Float16 f16x2;
typedef __attribute__((ext_vector_type(4))) _Float16 f16x4;
typedef __attribute__((ext_vector_type(8))) _Float16 f16x8;

__device__ __forceinline__ f32x4 mfma16x16x32(bf16x8 a, bf16x8 b, f32x4 c) {
    return __builtin_amdgcn_mfma_f32_16x16x32_bf16(a, b, c, 0, 0, 0);
}
__device__ __forceinline__ f32x4 mfma16x16x32h(f16x8 a, f16x8 b, f32x4 c) {
    return __builtin_amdgcn_mfma_f32_16x16x32_f16(a, b, c, 0, 0, 0);
}
// async global->LDS, 16B per lane; LDS dest = wave-uniform base + lane*16,
// global source is PER-LANE (pre-swizzle source for swizzled LDS layouts).
__device__ __forceinline__ void gload_lds16(const void* g, void* l) {
    __builtin_amdgcn_global_load_lds(
        (const __attribute__((address_space(1))) unsigned int*)g,
        (__attribute__((address_space(3))) unsigned int*)l, 16, 0, 0);
}

// ---------------------------------------------------------------------------
// Prep: fused X fp32->bf16 convert (blocks 0..1023) and W transpose+convert
// (blocks 1024..2047).
// ---------------------------------------------------------------------------
__global__ __launch_bounds__(256) void prep(
    const float* __restrict__ X,
    const float* __restrict__ Wq, const float* __restrict__ Wk,
    const float* __restrict__ Wv, const float* __restrict__ Wo,
    bf16* __restrict__ Xb, bf16* __restrict__ Wt)
{
    __shared__ bf16 tile[32][33];
    const int b = blockIdx.x;
    if (b < 1024) {
        int i = (b * 256 + threadIdx.x) * 8;
        float4 a = *(const float4*)(X + i);
        float4 c = *(const float4*)(X + i + 4);
        bf16 tmp[8];
        tmp[0] = __float2bfloat16(a.x); tmp[1] = __float2bfloat16(a.y);
        tmp[2] = __float2bfloat16(a.z); tmp[3] = __float2bfloat16(a.w);
        tmp[4] = __float2bfloat16(c.x); tmp[5] = __float2bfloat16(c.y);
        tmp[6] = __float2bfloat16(c.z); tmp[7] = __float2bfloat16(c.w);
        *(bf16x8*)(Xb + i) = *(bf16x8*)tmp;
    } else {
        const int bb = b - 1024;
        const int z = bb >> 8;
        const int bx = bb & 15, by = (bb >> 4) & 15;
        const float* src = (z == 0) ? Wq : (z == 1) ? Wk : (z == 2) ? Wv : Wo;
        bf16* dst = Wt + (size_t)z * DMODEL * DMODEL;
        const int tx = threadIdx.x & 31, ty = threadIdx.x >> 5;
        const int x = bx * 32 + tx;
        const int y0 = by * 32;
        #pragma unroll
        for (int i = ty; i < 32; i += 8)
            tile[i][tx] = __float2bfloat16(src[(size_t)(y0 + i) * DMODEL + x]);
        __syncthreads();
        const int xo = y0 + tx;
        #pragma unroll
        for (int i = ty; i < 32; i += 8)
            dst[(size_t)(bx * 32 + i) * DMODEL + xo] = tile[tx][i];
    }
}

// ---------------------------------------------------------------------------
// Fused QKV projection with A-TILE REUSE: block (m, nq) computes the Q, K and
// V 64x64 tiles for rows m*64, cols nq*64 -- one A-tile staged per k-step is
// shared by 3 B-tiles (24 MFMA/wave/step; 3x barrier amortization).
// grid 64x8 = 512 blocks. LDS 64KB: A dbuf 16KB + B dbuf 3x16KB.
// XOR-swizzled LDS (both-sides involution). Counted-vmcnt raw barriers.
// Epilogue: LDS-transpose -> fully coalesced 16B/lane stores for Q,K and the
// token-permuted Vt (pi(m)=((m>>2)&3)*16+(m>>4)*4+(m&3)).
// Q scaled by (1/8)*log2(e) (attn uses exp2).
// ---------------------------------------------------------------------------
__global__ __launch_bounds__(256) void gemm_qkv(
    const bf16* __restrict__ A, const bf16* __restrict__ Bt,
    bf16* __restrict__ Qm, bf16* __restrict__ Km, _Float16* __restrict__ Vt)
{
    __shared__ __align__(16) char smem[65536];
    const int m0 = blockIdx.x * 64, n0 = blockIdx.y * 64;
    const int t = threadIdx.x, lane = t & 63, w = t >> 6;
    const int lr = lane & 15, lq = lane >> 4;
    const int swz = (lr & 7) << 4;

    f32x4 acc[3][4];
    #pragma unroll
    for (int i = 0; i < 3; ++i)
        #pragma unroll
        for (int n = 0; n < 4; ++n) acc[i][n] = f32x4{0, 0, 0, 0};

    // staging: wave w instr i covers rows w*8+32i..+7; lane -> row +(lane>>3),
    // 16B chunk ((lane&7)^(lane>>3)) -- pre-swizzled source, linear LDS dest.
    const int srow = w * 8 + (lane >> 3);
    const int scol = ((lane & 7) ^ (lane >> 3)) * 8;
    const bf16* Ab = A + (size_t)(m0 + srow) * DMODEL + scol;
    const bf16* Bb = Bt + (size_t)(n0 + srow) * DMODEL + scol;

#define QKV_STAGE(k0, b) do {                                                  \
        char* ad = smem + (b) * 8192 + w * 1024;                               \
        gload_lds16(Ab + (k0), ad);                                            \
        gload_lds16(Ab + 32 * DMODEL + (k0), ad + 4096);                       \
        _Pragma("unroll")                                                      \
        for (int mat = 0; mat < 3; ++mat) {                                    \
            char* bd = smem + 16384 + ((b) * 3 + mat) * 8192 + w * 1024;       \
            gload_lds16(Bb + mat * DMODEL * DMODEL + (k0), bd);                \
            gload_lds16(Bb + mat * DMODEL * DMODEL + 32 * DMODEL + (k0), bd + 4096); \
        }                                                                      \
    } while (0)

    QKV_STAGE(0, 0);
    #pragma unroll
    for (int ks = 0; ks < 8; ++ks) {
        const int cur = ks & 1;
        if (ks < 7) {
            QKV_STAGE((ks + 1) * 64, cur ^ 1);
            asm volatile("s_waitcnt vmcnt(8)" ::: "memory");   // tile ks landed
        } else {
            asm volatile("s_waitcnt vmcnt(0)" ::: "memory");
        }
        __builtin_amdgcn_s_barrier();
        __builtin_amdgcn_sched_barrier(0);
        #pragma unroll
        for (int kc = 0; kc < 2; ++kc) {
            const int co = (kc * 64 + lq * 16) ^ swz;
            bf16x8 a = *(const bf16x8*)(smem + cur * 8192 + (w * 16 + lr) * 128 + co);
            #pragma unroll
            for (int mat = 0; mat < 3; ++mat)
                #pragma unroll
                for (int nt = 0; nt < 4; ++nt) {
                    bf16x8 b = *(const bf16x8*)(smem + 16384 + (cur * 3 + mat) * 8192 +
                                                (nt * 16 + lr) * 128 + co);
                    acc[mat][nt] = mfma16x16x32(a, b, acc[mat][nt]);
                }
        }
        asm volatile("s_waitcnt lgkmcnt(0)" ::: "memory");     // reads done before re-stage
        __builtin_amdgcn_sched_barrier(0);
        __builtin_amdgcn_s_barrier();
    }
#undef QKV_STAGE

    // ---- epilogue: LDS transpose (all three at once), coalesced stores ----
    bf16*     tbq = (bf16*)smem;               // [64][72] bf16
    bf16*     tbk = (bf16*)(smem + 9216);      // [64][72] bf16
    _Float16* tbv = (_Float16*)(smem + 18432); // [64][72] f16
    #pragma unroll
    for (int nt = 0; nt < 4; ++nt)
        #pragma unroll
        for (int r = 0; r < 4; ++r) {
            int row = w * 16 + lq * 4 + r, col = nt * 16 + lr;
            tbq[row * 72 + col] = __float2bfloat16(acc[0][nt][r] * 0.18033688f); // (1/8)*log2e
            tbk[row * 72 + col] = __float2bfloat16(acc[1][nt][r]);
            tbv[row * 72 + col] = (_Float16)acc[2][nt][r];
        }
    __syncthreads();
    // Q/K: 8 threads per row x 8 cols -> dense 128B-per-8-lanes stores
    #pragma unroll
    for (int pass = 0; pass < 2; ++pass) {
        const int m = pass * 32 + (t >> 3), c0 = (t & 7) * 8;
        *(bf16x8*)(Qm + (size_t)(m0 + m) * DMODEL + n0 + c0) =
            *(const bf16x8*)(tbq + m * 72 + c0);
        *(bf16x8*)(Km + (size_t)(m0 + m) * DMODEL + n0 + c0) =
            *(const bf16x8*)(tbk + m * 72 + c0);
    }
    // V: token-permuted coalesced stores (pi = digit transpose)
    {
        const int c = t >> 2, seg = t & 3;      // c: hd col 0..63, seg: 16-row chunk
        _Float16 tmp[16];
        #pragma unroll
        for (int j = 0; j < 16; ++j)
            tmp[j] = tbv[(seg * 16 + j) * 72 + c];
        _Float16* vp = Vt + (size_t)(n0 + c) * S_LEN + m0;
        #pragma unroll
        for (int g = 0; g < 4; ++g) {
            f16x4 vv = {tmp[g * 4 + 0], tmp[g * 4 + 1], tmp[g * 4 + 2], tmp[g * 4 + 3]};
            *(f16x4*)(vp + g * 16 + seg * 4) = vv;
        }
    }
}

// ---------------------------------------------------------------------------
// Out projection: 64x64 tiles (grid 64x8), dbuf + swizzle + counted vmcnt.
// Epilogue: bias add + LDS transpose -> dense fp32 stores (was 4-col scatter).
// ---------------------------------------------------------------------------
__global__ __launch_bounds__(256) void gemm_out(
    const bf16* __restrict__ A, const bf16* __restrict__ Bt,
    float* __restrict__ Out, const float* __restrict__ bias)
{
    __shared__ __align__(16) char smem[32768];  // A dbuf 16KB + B dbuf 16KB; epilogue tb aliases
    const int m0 = blockIdx.x * 64, n0 = blockIdx.y * 64;
    const int t = threadIdx.x, lane = t & 63, w = t >> 6;
    const int lr = lane & 15, lq = lane >> 4;
    const int swz = (lr & 7) << 4;

    f32x4 acc[4] = {f32x4{0,0,0,0}, f32x4{0,0,0,0}, f32x4{0,0,0,0}, f32x4{0,0,0,0}};

    const int srow = w * 8 + (lane >> 3);
    const int scol = ((lane & 7) ^ (lane >> 3)) * 8;
    const bf16* Ab = A + (size_t)(m0 + srow) * DMODEL + scol;
    const bf16* Bb = Bt + (size_t)(n0 + srow) * DMODEL + scol;

#define OUT_STAGE(k0, b) do {                                           \
        char* ad = smem + (b) * 8192 + w * 1024;                        \
        char* bd = smem + 16384 + (b) * 8192 + w * 1024;                \
        gload_lds16(Ab + (k0), ad);                                     \
        gload_lds16(Ab + 32 * DMODEL + (k0), ad + 4096);                \
        gload_lds16(Bb + (k0), bd);                                     \
        gload_lds16(Bb + 32 * DMODEL + (k0), bd + 4096);                \
    } while (0)

    OUT_STAGE(0, 0);
    #pragma unroll
    for (int ks = 0; ks < 8; ++ks) {
        const int cur = ks & 1;
        if (ks < 7) {
            OUT_STAGE((ks + 1) * 64, cur ^ 1);
            asm volatile("s_waitcnt vmcnt(4)" ::: "memory");
        } else {
            asm volatile("s_waitcnt vmcnt(0)" ::: "memory");
        }
        __builtin_amdgcn_s_barrier();
        __builtin_amdgcn_sched_barrier(0);
        #pragma unroll
        for (int kc = 0; kc < 2; ++kc) {
            const int co = (kc * 64 + lq * 16) ^ swz;
            bf16x8 a = *(const bf16x8*)(smem + cur * 8192 + (w * 16 + lr) * 128 + co);
            #pragma unroll
            for (int nt = 0; nt < 4; ++nt) {
                bf16x8 b = *(const bf16x8*)(smem + 16384 + cur * 8192 + (nt * 16 + lr) * 128 + co);
                acc[nt] = mfma16x16x32(a, b, acc[nt]);
            }
        }
        asm volatile("s_waitcnt lgkmcnt(0)" ::: "memory");
        __builtin_amdgcn_sched_barrier(0);
        __builtin_amdgcn_s_barrier();
    }
#undef OUT_STAGE

    // epilogue: bias + LDS transpose -> dense fp32 stores
    float* tb = (float*)smem;   // [64][68] f32 = 17408B (aliases dead dbuf)
    #pragma unroll
    for (int nt = 0; nt < 4; ++nt) {
        const float bv = bias[n0 + nt * 16 + lr];
        #pragma unroll
        for (int r = 0; r < 4; ++r)
            tb[(w * 16 + lq * 4 + r) * 68 + nt * 16 + lr] = acc[nt][r] + bv;
    }
    __syncthreads();
    #pragma unroll
    for (int pass = 0; pass < 2; ++pass) {
        const int m = pass * 32 + (t >> 3), c0 = (t & 7) * 8;
        float4 v0 = *(const float4*)(tb + m * 68 + c0);
        float4 v1 = *(const float4*)(tb + m * 68 + c0 + 4);
        *(float4*)(Out + (size_t)(m0 + m) * DMODEL + n0 + c0) = v0;
        *(float4*)(Out + (size_t)(m0 + m) * DMODEL + n0 + c0 + 4) = v1;
    }
}

// ---------------------------------------------------------------------------
// Attention v6: wave-decoupled kt-split, per-wave LDS staging.
// Change vs r8: PV via mfma_f32_16x16x32_f16 (32 instead of 64 MFMA/iter;
// the round-4 V token-permutation makes vA/vB exact K=32 B-frags and
// concat(pf0,pf1)/(pf2,pf3) the matching A-frags -- identical numerics),
// and packed f32->f16 converts via v_cvt_pkrtz (64 -> 32 VALU ops).
// grid (H, S/64): block id % 8 == head -> per-XCD L2-resident K/V.
// ---------------------------------------------------------------------------
__global__ __launch_bounds__(256, 2) void attn_kernel(
    const bf16* __restrict__ Q, const bf16* __restrict__ Kmat,
    const _Float16* __restrict__ Vt, bf16* __restrict__ Oout)
{
    __shared__ __align__(16) char smem[65536];  // 4 waves x (8KB K + 8KB V); epilogue aliases

    const int h = blockIdx.x, qb = blockIdx.y;
    const int t = threadIdx.x, lane = t & 63, w = t >> 6;
    const int lr = lane & 15, lq = lane >> 4;
    const int q0 = qb * 64;

    char* myK = smem + w * 16384;       // [64 rows][128B]  K tile (bf16)
    char* myV = myK + 8192;             // [64 hd  ][128B]  V^T tile (f16, token-permuted)

    const int sr = lane >> 3;
    const int scc = (lane & 7) ^ sr;                 // pre-swizzled global chunk
    const bf16*     gK = Kmat + (size_t)sr * DMODEL + h * HDIM + scc * 8;
    const _Float16* gV = Vt + (size_t)(h * HDIM + sr) * S_LEN + scc * 8;

    // Q B-frags for all 4 qt tiles
    bf16x8 qf[4][2];
    #pragma unroll
    for (int qt = 0; qt < 4; ++qt) {
        const bf16* qp = Q + (size_t)(q0 + qt * 16 + lr) * DMODEL + h * HDIM + lq * 8;
        qf[qt][0] = *(const bf16x8*)qp;
        qf[qt][1] = *(const bf16x8*)(qp + 32);
    }

    f32x4 oacc[4][4];   // [qt][ht]; C: row(Q)=lq*4+r, col(hd)=lr
    #pragma unroll
    for (int i = 0; i < 4; ++i)
        #pragma unroll
        for (int j = 0; j < 4; ++j) oacc[i][j] = f32x4{0, 0, 0, 0};
    float lsum[4] = {0, 0, 0, 0};

    // prologue: stage first tile (kt = w)
    #pragma unroll
    for (int i = 0; i < 8; ++i) {
        gload_lds16(gK + (size_t)(w * 64 + i * 8) * DMODEL, myK + i * 1024);
        gload_lds16(gV + (size_t)(i * 8) * S_LEN + w * 64, myV + i * 1024);
    }

    const int swz = (lr & 7) << 4;

    for (int kt = w; kt < S_LEN / 64; kt += 4) {
        asm volatile("s_waitcnt vmcnt(0)" ::: "memory");  // staged tile landed

        // K frags (swizzled ds_read_b128, 2-way max)
        bf16x8 kf[4][2];
        #pragma unroll
        for (int mt = 0; mt < 4; ++mt) {
            const char* kr = myK + (mt * 16 + lr) * 128;
            kf[mt][0] = *(const bf16x8*)(kr + ((lq * 16) ^ swz));
            kf[mt][1] = *(const bf16x8*)(kr + ((64 + lq * 16) ^ swz));
        }
        // V frags: token-permuted layout -> contiguous 32B = 2 swizzled b128/ht
        f16x8 vA[4], vB[4];   // [ht]: vA = tokens 0..31 (K=32 B-frag), vB = 32..63
        #pragma unroll
        for (int ht = 0; ht < 4; ++ht) {
            const char* vr = myV + (ht * 16 + lr) * 128;
            vA[ht] = *(const f16x8*)(vr + ((lq * 32) ^ swz));
            vB[ht] = *(const f16x8*)(vr + ((lq * 32 + 16) ^ swz));
        }
        asm volatile("s_waitcnt lgkmcnt(0)" ::: "memory");
        __builtin_amdgcn_sched_barrier(0);

        // issue-early prefetch of next tile (overlaps with compute below)
        const int ktn = kt + 4;
        if (ktn < S_LEN / 64) {
            #pragma unroll
            for (int i = 0; i < 8; ++i) {
                gload_lds16(gK + (size_t)(ktn * 64 + i * 8) * DMODEL, myK + i * 1024);
                gload_lds16(gV + (size_t)(i * 8) * S_LEN + ktn * 64, myV + i * 1024);
            }
        }

        __builtin_amdgcn_s_setprio(1);
        // S^T = K @ Q^T ; P = exp2(S^T)  (log2e folded into Q)
        f16x4 pf[4][4];   // [qt][mt]
        #pragma unroll
        for (int qt = 0; qt < 4; ++qt) {
            f32x4 st[4];
            #pragma unroll
            for (int mt = 0; mt < 4; ++mt) {
                f32x4 z = {0, 0, 0, 0};
                z = mfma16x16x32(kf[mt][0], qf[qt][0], z);
                z = mfma16x16x32(kf[mt][1], qf[qt][1], z);
                st[mt] = z;
            }
            #pragma unroll
            for (int mt = 0; mt < 4; ++mt) {
                float p0 = __builtin_amdgcn_exp2f(st[mt][0]);
                float p1 = __builtin_amdgcn_exp2f(st[mt][1]);
                float p2 = __builtin_amdgcn_exp2f(st[mt][2]);
                float p3 = __builtin_amdgcn_exp2f(st[mt][3]);
                lsum[qt] += (p0 + p1) + (p2 + p3);
                f16x2 c01 = __builtin_bit_cast(f16x2, __builtin_amdgcn_cvt_pkrtz(p0, p1));
                f16x2 c23 = __builtin_bit_cast(f16x2, __builtin_amdgcn_cvt_pkrtz(p2, p3));
                pf[qt][mt] = __builtin_shufflevector(c01, c23, 0, 1, 2, 3);
            }
        }
        // O += P @ V  (K=32 f16 MFMA; A = concat of two 16-token P frags)
        #pragma unroll
        for (int qt = 0; qt < 4; ++qt) {
            f16x8 pp01 = __builtin_shufflevector(pf[qt][0], pf[qt][1], 0, 1, 2, 3, 4, 5, 6, 7);
            f16x8 pp23 = __builtin_shufflevector(pf[qt][2], pf[qt][3], 0, 1, 2, 3, 4, 5, 6, 7);
            #pragma unroll
            for (int ht = 0; ht < 4; ++ht) {
                oacc[qt][ht] = mfma16x16x32h(pp01, vA[ht], oacc[qt][ht]);
                oacc[qt][ht] = mfma16x16x32h(pp23, vB[ht], oacc[qt][ht]);
            }
        }
        __builtin_amdgcn_s_setprio(0);
    }

    // ---- cross-wave combine; obuf ALIASES the staging LDS ----
    __syncthreads();
    float (*obuf)[3][4][64][4] = (float(*)[3][4][64][4])smem;   // 48KB
    float (*lbuf)[4][16]       = (float(*)[4][16])(smem + 49152);

    #pragma unroll
    for (int qt = 0; qt < 4; ++qt) {
        if (qt != w) {
            int j = qt - (qt > w ? 1 : 0);
            #pragma unroll
            for (int ht = 0; ht < 4; ++ht)
                *(f32x4*)&obuf[w][j][ht][lane][0] = oacc[qt][ht];
        }
    }
    // row sums: reduce over lq groups, publish
    #pragma unroll
    for (int qt = 0; qt < 4; ++qt) {
        float s = lsum[qt];
        s += __shfl_xor(s, 16);
        s += __shfl_xor(s, 32);
        if (lq == 0) lbuf[w][qt][lr] = s;
    }
    __syncthreads();

    // wave w finalizes qt == w
    f32x4 osum[4];
    #pragma unroll
    for (int qt = 0; qt < 4; ++qt)
        if (qt == w) {
            #pragma unroll
            for (int ht = 0; ht < 4; ++ht) osum[ht] = oacc[qt][ht];
        }
    #pragma unroll
    for (int w2 = 0; w2 < 4; ++w2) {
        if (w2 == w) continue;
        int j = w - (w > w2 ? 1 : 0);
        #pragma unroll
        for (int ht = 0; ht < 4; ++ht)
            osum[ht] += *(const f32x4*)&obuf[w2][j][ht][lane][0];
    }
    float linv[4];
    #pragma unroll
    for (int r = 0; r < 4; ++r) {
        int rr = lq * 4 + r;
        linv[r] = 1.0f / (lbuf[0][w][rr] + lbuf[1][w][rr] + lbuf[2][w][rr] + lbuf[3][w][rr]);
    }
    #pragma unroll
    for (int r = 0; r < 4; ++r) {
        int row = q0 + w * 16 + lq * 4 + r;
        #pragma unroll
        for (int ht = 0; ht < 4; ++ht)
            Oout[(size_t)row * DMODEL + h * HDIM + ht * 16 + lr] =
                __float2bfloat16(osum[ht][r] * linv[r]);
    }
}

// ---------------------------------------------------------------------------
extern "C" void kernel_launch(void* const* d_in, const int* in_sizes, int n_in,
                              void* d_out, int out_size, void* d_ws, size_t ws_size,
                              hipStream_t stream) {
    const float* X  = (const float*)d_in[0];
    const float* Wq = (const float*)d_in[1];
    const float* Wk = (const float*)d_in[2];
    const float* Wv = (const float*)d_in[3];
    const float* Wo = (const float*)d_in[4];
    const float* bo = (const float*)d_in[5];
    float* out = (float*)d_out;

    char* ws = (char*)d_ws;
    bf16* Wt = (bf16*)ws;                                  // [4][512][512] bf16
    bf16* Xb = (bf16*)(ws + (size_t)4 * DMODEL * DMODEL * 2);
    bf16* Qm = Xb + (size_t)S_LEN * DMODEL;
    bf16* Km = Qm + (size_t)S_LEN * DMODEL;
    _Float16* Vt = (_Float16*)(Km + (size_t)S_LEN * DMODEL);   // [512][4096] f16 (permuted)
    bf16* AO = (bf16*)(Vt + (size_t)S_LEN * DMODEL);

    bf16* Wot = Wt + (size_t)3 * DMODEL * DMODEL;

    prep<<<2048, 256, 0, stream>>>(X, Wq, Wk, Wv, Wo, Xb, Wt);

    gemm_qkv<<<dim3(S_LEN / 64, DMODEL / 64), 256, 0, stream>>>(
        Xb, Wt, Qm, Km, Vt);

    attn_kernel<<<dim3(NHEADS, S_LEN / 64), 256, 0, stream>>>(Qm, Km, Vt, AO);

    gemm_out<<<dim3(S_LEN / 64, DMODEL / 64), 256, 0, stream>>>(AO, Wot, out, bo);
}

// Round 13
// 125.765 us; speedup vs baseline: 1.1478x; 1.0198x over previous
//
#include <hip/hip_runtime.h>
#include <hip/hip_bf16.h>

#define S_LEN 4096
#define DMODEL 512
#define NHEADS 8
#define HDIM 64

typedef __hip_bfloat16 bf16;
typedef __attribute__((ext_vector_type(8))) short bf16x8;
typedef __attribute__((ext_vector_type(4))) float f32x4;
typedef __attribute__((ext_vector_type(2))) _Float16 f16x2;
typedef __attribute__((ext_vector_type(4))) _Float16 f16x4;
typedef __attribute__((ext_vector_type(8))) _Float16 f16x8;

__device__ __forceinline__ f32x4 mfma16x16x32(bf16x8 a, bf16x8 b, f32x4 c) {
    return __builtin_amdgcn_mfma_f32_16x16x32_bf16(a, b, c, 0, 0, 0);
}
__device__ __forceinline__ f32x4 mfma16x16x32h(f16x8 a, f16x8 b, f32x4 c) {
    return __builtin_amdgcn_mfma_f32_16x16x32_f16(a, b, c, 0, 0, 0);
}
// async global->LDS, 16B per lane; LDS dest = wave-uniform base + lane*16,
// global source is PER-LANE (pre-swizzle source for swizzled LDS layouts).
__device__ __forceinline__ void gload_lds16(const void* g, void* l) {
    __builtin_amdgcn_global_load_lds(
        (const __attribute__((address_space(1))) unsigned int*)g,
        (__attribute__((address_space(3))) unsigned int*)l, 16, 0, 0);
}

// ---------------------------------------------------------------------------
// Prep: fused X fp32->bf16 convert (blocks 0..1023) and W transpose+convert
// (blocks 1024..2047).
// ---------------------------------------------------------------------------
__global__ __launch_bounds__(256) void prep(
    const float* __restrict__ X,
    const float* __restrict__ Wq, const float* __restrict__ Wk,
    const float* __restrict__ Wv, const float* __restrict__ Wo,
    bf16* __restrict__ Xb, bf16* __restrict__ Wt)
{
    __shared__ bf16 tile[32][33];
    const int b = blockIdx.x;
    if (b < 1024) {
        int i = (b * 256 + threadIdx.x) * 8;
        float4 a = *(const float4*)(X + i);
        float4 c = *(const float4*)(X + i + 4);
        bf16 tmp[8];
        tmp[0] = __float2bfloat16(a.x); tmp[1] = __float2bfloat16(a.y);
        tmp[2] = __float2bfloat16(a.z); tmp[3] = __float2bfloat16(a.w);
        tmp[4] = __float2bfloat16(c.x); tmp[5] = __float2bfloat16(c.y);
        tmp[6] = __float2bfloat16(c.z); tmp[7] = __float2bfloat16(c.w);
        *(bf16x8*)(Xb + i) = *(bf16x8*)tmp;
    } else {
        const int bb = b - 1024;
        const int z = bb >> 8;
        const int bx = bb & 15, by = (bb >> 4) & 15;
        const float* src = (z == 0) ? Wq : (z == 1) ? Wk : (z == 2) ? Wv : Wo;
        bf16* dst = Wt + (size_t)z * DMODEL * DMODEL;
        const int tx = threadIdx.x & 31, ty = threadIdx.x >> 5;
        const int x = bx * 32 + tx;
        const int y0 = by * 32;
        #pragma unroll
        for (int i = ty; i < 32; i += 8)
            tile[i][tx] = __float2bfloat16(src[(size_t)(y0 + i) * DMODEL + x]);
        __syncthreads();
        const int xo = y0 + tx;
        #pragma unroll
        for (int i = ty; i < 32; i += 8)
            dst[(size_t)(bx * 32 + i) * DMODEL + xo] = tile[tx][i];
    }
}

// ---------------------------------------------------------------------------
// Fused QKV projection with A-TILE REUSE: block (m, nq) computes the Q, K and
// V 64x64 tiles for rows m*64, cols nq*64 -- one A-tile staged per k-step is
// shared by 3 B-tiles (24 MFMA/wave/step; 3x barrier amortization).
// grid 64x8 = 512 blocks. LDS 64KB: A dbuf 16KB + B dbuf 3x16KB.
// XOR-swizzled LDS (both-sides involution). Counted-vmcnt raw barriers.
// Epilogue: LDS-transpose -> fully coalesced 16B/lane stores for Q,K and the
// token-permuted Vt (pi(m)=((m>>2)&3)*16+(m>>4)*4+(m&3)).
// Q scaled by (1/8)*log2(e) (attn uses exp2).
// ---------------------------------------------------------------------------
__global__ __launch_bounds__(256) void gemm_qkv(
    const bf16* __restrict__ A, const bf16* __restrict__ Bt,
    bf16* __restrict__ Qm, bf16* __restrict__ Km, _Float16* __restrict__ Vt)
{
    __shared__ __align__(16) char smem[65536];
    const int m0 = blockIdx.x * 64, n0 = blockIdx.y * 64;
    const int t = threadIdx.x, lane = t & 63, w = t >> 6;
    const int lr = lane & 15, lq = lane >> 4;
    const int swz = (lr & 7) << 4;

    f32x4 acc[3][4];
    #pragma unroll
    for (int i = 0; i < 3; ++i)
        #pragma unroll
        for (int n = 0; n < 4; ++n) acc[i][n] = f32x4{0, 0, 0, 0};

    // staging: wave w instr i covers rows w*8+32i..+7; lane -> row +(lane>>3),
    // 16B chunk ((lane&7)^(lane>>3)) -- pre-swizzled source, linear LDS dest.
    const int srow = w * 8 + (lane >> 3);
    const int scol = ((lane & 7) ^ (lane >> 3)) * 8;
    const bf16* Ab = A + (size_t)(m0 + srow) * DMODEL + scol;
    const bf16* Bb = Bt + (size_t)(n0 + srow) * DMODEL + scol;

#define QKV_STAGE(k0, b) do {                                                  \
        char* ad = smem + (b) * 8192 + w * 1024;                               \
        gload_lds16(Ab + (k0), ad);                                            \
        gload_lds16(Ab + 32 * DMODEL + (k0), ad + 4096);                       \
        _Pragma("unroll")                                                      \
        for (int mat = 0; mat < 3; ++mat) {                                    \
            char* bd = smem + 16384 + ((b) * 3 + mat) * 8192 + w * 1024;       \
            gload_lds16(Bb + mat * DMODEL * DMODEL + (k0), bd);                \
            gload_lds16(Bb + mat * DMODEL * DMODEL + 32 * DMODEL + (k0), bd + 4096); \
        }                                                                      \
    } while (0)

    QKV_STAGE(0, 0);
    #pragma unroll
    for (int ks = 0; ks < 8; ++ks) {
        const int cur = ks & 1;
        if (ks < 7) {
            QKV_STAGE((ks + 1) * 64, cur ^ 1);
            asm volatile("s_waitcnt vmcnt(8)" ::: "memory");   // tile ks landed
        } else {
            asm volatile("s_waitcnt vmcnt(0)" ::: "memory");
        }
        __builtin_amdgcn_s_barrier();
        __builtin_amdgcn_sched_barrier(0);
        #pragma unroll
        for (int kc = 0; kc < 2; ++kc) {
            const int co = (kc * 64 + lq * 16) ^ swz;
            bf16x8 a = *(const bf16x8*)(smem + cur * 8192 + (w * 16 + lr) * 128 + co);
            #pragma unroll
            for (int mat = 0; mat < 3; ++mat)
                #pragma unroll
                for (int nt = 0; nt < 4; ++nt) {
                    bf16x8 b = *(const bf16x8*)(smem + 16384 + (cur * 3 + mat) * 8192 +
                                                (nt * 16 + lr) * 128 + co);
                    acc[mat][nt] = mfma16x16x32(a, b, acc[mat][nt]);
                }
        }
        asm volatile("s_waitcnt lgkmcnt(0)" ::: "memory");     // reads done before re-stage
        __builtin_amdgcn_sched_barrier(0);
        __builtin_amdgcn_s_barrier();
    }
#undef QKV_STAGE

    // ---- epilogue: LDS transpose (all three at once), coalesced stores ----
    bf16*     tbq = (bf16*)smem;               // [64][72] bf16
    bf16*     tbk = (bf16*)(smem + 9216);      // [64][72] bf16
    _Float16* tbv = (_Float16*)(smem + 18432); // [64][72] f16
    #pragma unroll
    for (int nt = 0; nt < 4; ++nt)
        #pragma unroll
        for (int r = 0; r < 4; ++r) {
            int row = w * 16 + lq * 4 + r, col = nt * 16 + lr;
            tbq[row * 72 + col] = __float2bfloat16(acc[0][nt][r] * 0.18033688f); // (1/8)*log2e
            tbk[row * 72 + col] = __float2bfloat16(acc[1][nt][r]);
            tbv[row * 72 + col] = (_Float16)acc[2][nt][r];
        }
    __syncthreads();
    // Q/K: 8 threads per row x 8 cols -> dense 128B-per-8-lanes stores
    #pragma unroll
    for (int pass = 0; pass < 2; ++pass) {
        const int m = pass * 32 + (t >> 3), c0 = (t & 7) * 8;
        *(bf16x8*)(Qm + (size_t)(m0 + m) * DMODEL + n0 + c0) =
            *(const bf16x8*)(tbq + m * 72 + c0);
        *(bf16x8*)(Km + (size_t)(m0 + m) * DMODEL + n0 + c0) =
            *(const bf16x8*)(tbk + m * 72 + c0);
    }
    // V: token-permuted coalesced stores (pi = digit transpose)
    {
        const int c = t >> 2, seg = t & 3;      // c: hd col 0..63, seg: 16-row chunk
        _Float16 tmp[16];
        #pragma unroll
        for (int j = 0; j < 16; ++j)
            tmp[j] = tbv[(seg * 16 + j) * 72 + c];
        _Float16* vp = Vt + (size_t)(n0 + c) * S_LEN + m0;
        #pragma unroll
        for (int g = 0; g < 4; ++g) {
            f16x4 vv = {tmp[g * 4 + 0], tmp[g * 4 + 1], tmp[g * 4 + 2], tmp[g * 4 + 3]};
            *(f16x4*)(vp + g * 16 + seg * 4) = vv;
        }
    }
}

// ---------------------------------------------------------------------------
// Out projection: 64x64 tiles (grid 64x8), dbuf + swizzle + counted vmcnt.
// Epilogue: bias add + LDS transpose -> dense fp32 stores.
// ---------------------------------------------------------------------------
__global__ __launch_bounds__(256) void gemm_out(
    const bf16* __restrict__ A, const bf16* __restrict__ Bt,
    float* __restrict__ Out, const float* __restrict__ bias)
{
    __shared__ __align__(16) char smem[32768];  // A dbuf 16KB + B dbuf 16KB; epilogue tb aliases
    const int m0 = blockIdx.x * 64, n0 = blockIdx.y * 64;
    const int t = threadIdx.x, lane = t & 63, w = t >> 6;
    const int lr = lane & 15, lq = lane >> 4;
    const int swz = (lr & 7) << 4;

    f32x4 acc[4] = {f32x4{0,0,0,0}, f32x4{0,0,0,0}, f32x4{0,0,0,0}, f32x4{0,0,0,0}};

    const int srow = w * 8 + (lane >> 3);
    const int scol = ((lane & 7) ^ (lane >> 3)) * 8;
    const bf16* Ab = A + (size_t)(m0 + srow) * DMODEL + scol;
    const bf16* Bb = Bt + (size_t)(n0 + srow) * DMODEL + scol;

#define OUT_STAGE(k0, b) do {                                           \
        char* ad = smem + (b) * 8192 + w * 1024;                        \
        char* bd = smem + 16384 + (b) * 8192 + w * 1024;                \
        gload_lds16(Ab + (k0), ad);                                     \
        gload_lds16(Ab + 32 * DMODEL + (k0), ad + 4096);                \
        gload_lds16(Bb + (k0), bd);                                     \
        gload_lds16(Bb + 32 * DMODEL + (k0), bd + 4096);                \
    } while (0)

    OUT_STAGE(0, 0);
    #pragma unroll
    for (int ks = 0; ks < 8; ++ks) {
        const int cur = ks & 1;
        if (ks < 7) {
            OUT_STAGE((ks + 1) * 64, cur ^ 1);
            asm volatile("s_waitcnt vmcnt(4)" ::: "memory");
        } else {
            asm volatile("s_waitcnt vmcnt(0)" ::: "memory");
        }
        __builtin_amdgcn_s_barrier();
        __builtin_amdgcn_sched_barrier(0);
        #pragma unroll
        for (int kc = 0; kc < 2; ++kc) {
            const int co = (kc * 64 + lq * 16) ^ swz;
            bf16x8 a = *(const bf16x8*)(smem + cur * 8192 + (w * 16 + lr) * 128 + co);
            #pragma unroll
            for (int nt = 0; nt < 4; ++nt) {
                bf16x8 b = *(const bf16x8*)(smem + 16384 + cur * 8192 + (nt * 16 + lr) * 128 + co);
                acc[nt] = mfma16x16x32(a, b, acc[nt]);
            }
        }
        asm volatile("s_waitcnt lgkmcnt(0)" ::: "memory");
        __builtin_amdgcn_sched_barrier(0);
        __builtin_amdgcn_s_barrier();
    }
#undef OUT_STAGE

    // epilogue: bias + LDS transpose -> dense fp32 stores
    float* tb = (float*)smem;   // [64][68] f32 = 17408B (aliases dead dbuf)
    #pragma unroll
    for (int nt = 0; nt < 4; ++nt) {
        const float bv = bias[n0 + nt * 16 + lr];
        #pragma unroll
        for (int r = 0; r < 4; ++r)
            tb[(w * 16 + lq * 4 + r) * 68 + nt * 16 + lr] = acc[nt][r] + bv;
    }
    __syncthreads();
    #pragma unroll
    for (int pass = 0; pass < 2; ++pass) {
        const int m = pass * 32 + (t >> 3), c0 = (t & 7) * 8;
        float4 v0 = *(const float4*)(tb + m * 68 + c0);
        float4 v1 = *(const float4*)(tb + m * 68 + c0 + 4);
        *(float4*)(Out + (size_t)(m0 + m) * DMODEL + n0 + c0) = v0;
        *(float4*)(Out + (size_t)(m0 + m) * DMODEL + n0 + c0 + 4) = v1;
    }
}

// ---------------------------------------------------------------------------
// Attention v7: wave-decoupled kt-split, per-wave LDS staging.
// Row-sum via ones-vector K=32 MFMA (8 MFMA/iter replaces 48 VALU adds).
// r10 counters: VALU 40.8 > MFMA 31.7 -- regime favors the matrix pipe.
// grid (H, S/64): block id % 8 == head -> per-XCD L2-resident K/V.
// ---------------------------------------------------------------------------
__global__ __launch_bounds__(256, 2) void attn_kernel(
    const bf16* __restrict__ Q, const bf16* __restrict__ Kmat,
    const _Float16* __restrict__ Vt, bf16* __restrict__ Oout)
{
    __shared__ __align__(16) char smem[65536];  // 4 waves x (8KB K + 8KB V); epilogue aliases

    const int h = blockIdx.x, qb = blockIdx.y;
    const int t = threadIdx.x, lane = t & 63, w = t >> 6;
    const int lr = lane & 15, lq = lane >> 4;
    const int q0 = qb * 64;

    char* myK = smem + w * 16384;       // [64 rows][128B]  K tile (bf16)
    char* myV = myK + 8192;             // [64 hd  ][128B]  V^T tile (f16, token-permuted)

    const int sr = lane >> 3;
    const int scc = (lane & 7) ^ sr;                 // pre-swizzled global chunk
    const bf16*     gK = Kmat + (size_t)sr * DMODEL + h * HDIM + scc * 8;
    const _Float16* gV = Vt + (size_t)(h * HDIM + sr) * S_LEN + scc * 8;

    // Q B-frags for all 4 qt tiles
    bf16x8 qf[4][2];
    #pragma unroll
    for (int qt = 0; qt < 4; ++qt) {
        const bf16* qp = Q + (size_t)(q0 + qt * 16 + lr) * DMODEL + h * HDIM + lq * 8;
        qf[qt][0] = *(const bf16x8*)qp;
        qf[qt][1] = *(const bf16x8*)(qp + 32);
    }

    f32x4 oacc[4][4];   // [qt][ht]; C: row(Q)=lq*4+r, col(hd)=lr
    #pragma unroll
    for (int i = 0; i < 4; ++i)
        #pragma unroll
        for (int j = 0; j < 4; ++j) oacc[i][j] = f32x4{0, 0, 0, 0};
    f32x4 lacc[4];      // [qt] row sums via ones-MFMA (all cols identical)
    #pragma unroll
    for (int i = 0; i < 4; ++i) lacc[i] = f32x4{0, 0, 0, 0};
    const f16x8 vones = {(_Float16)1.0f, (_Float16)1.0f, (_Float16)1.0f, (_Float16)1.0f,
                         (_Float16)1.0f, (_Float16)1.0f, (_Float16)1.0f, (_Float16)1.0f};

    // prologue: stage first tile (kt = w)
    #pragma unroll
    for (int i = 0; i < 8; ++i) {
        gload_lds16(gK + (size_t)(w * 64 + i * 8) * DMODEL, myK + i * 1024);
        gload_lds16(gV + (size_t)(i * 8) * S_LEN + w * 64, myV + i * 1024);
    }

    const int swz = (lr & 7) << 4;

    for (int kt = w; kt < S_LEN / 64; kt += 4) {
        asm volatile("s_waitcnt vmcnt(0)" ::: "memory");  // staged tile landed

        // K frags (swizzled ds_read_b128, 2-way max)
        bf16x8 kf[4][2];
        #pragma unroll
        for (int mt = 0; mt < 4; ++mt) {
            const char* kr = myK + (mt * 16 + lr) * 128;
            kf[mt][0] = *(const bf16x8*)(kr + ((lq * 16) ^ swz));
            kf[mt][1] = *(const bf16x8*)(kr + ((64 + lq * 16) ^ swz));
        }
        // V frags: token-permuted layout -> contiguous 32B = 2 swizzled b128/ht
        f16x8 vA[4], vB[4];   // [ht]: vA = tokens 0..31 (K=32 B-frag), vB = 32..63
        #pragma unroll
        for (int ht = 0; ht < 4; ++ht) {
            const char* vr = myV + (ht * 16 + lr) * 128;
            vA[ht] = *(const f16x8*)(vr + ((lq * 32) ^ swz));
            vB[ht] = *(const f16x8*)(vr + ((lq * 32 + 16) ^ swz));
        }
        asm volatile("s_waitcnt lgkmcnt(0)" ::: "memory");
        __builtin_amdgcn_sched_barrier(0);

        // issue-early prefetch of next tile (overlaps with compute below)
        const int ktn = kt + 4;
        if (ktn < S_LEN / 64) {
            #pragma unroll
            for (int i = 0; i < 8; ++i) {
                gload_lds16(gK + (size_t)(ktn * 64 + i * 8) * DMODEL, myK + i * 1024);
                gload_lds16(gV + (size_t)(i * 8) * S_LEN + ktn * 64, myV + i * 1024);
            }
        }

        __builtin_amdgcn_s_setprio(1);
        // S^T = K @ Q^T ; P = exp2(S^T)  (log2e folded into Q)
        f16x4 pf[4][4];   // [qt][mt]
        #pragma unroll
        for (int qt = 0; qt < 4; ++qt) {
            f32x4 st[4];
            #pragma unroll
            for (int mt = 0; mt < 4; ++mt) {
                f32x4 z = {0, 0, 0, 0};
                z = mfma16x16x32(kf[mt][0], qf[qt][0], z);
                z = mfma16x16x32(kf[mt][1], qf[qt][1], z);
                st[mt] = z;
            }
            #pragma unroll
            for (int mt = 0; mt < 4; ++mt) {
                float p0 = __builtin_amdgcn_exp2f(st[mt][0]);
                float p1 = __builtin_amdgcn_exp2f(st[mt][1]);
                float p2 = __builtin_amdgcn_exp2f(st[mt][2]);
                float p3 = __builtin_amdgcn_exp2f(st[mt][3]);
                f16x2 c01 = __builtin_bit_cast(f16x2, __builtin_amdgcn_cvt_pkrtz(p0, p1));
                f16x2 c23 = __builtin_bit_cast(f16x2, __builtin_amdgcn_cvt_pkrtz(p2, p3));
                pf[qt][mt] = __builtin_shufflevector(c01, c23, 0, 1, 2, 3);
            }
        }
        // O += P @ V  (K=32 f16 MFMA) and row sums on the matrix pipe
        #pragma unroll
        for (int qt = 0; qt < 4; ++qt) {
            f16x8 pp01 = __builtin_shufflevector(pf[qt][0], pf[qt][1], 0, 1, 2, 3, 4, 5, 6, 7);
            f16x8 pp23 = __builtin_shufflevector(pf[qt][2], pf[qt][3], 0, 1, 2, 3, 4, 5, 6, 7);
            #pragma unroll
            for (int ht = 0; ht < 4; ++ht) {
                oacc[qt][ht] = mfma16x16x32h(pp01, vA[ht], oacc[qt][ht]);
                oacc[qt][ht] = mfma16x16x32h(pp23, vB[ht], oacc[qt][ht]);
            }
            lacc[qt] = mfma16x16x32h(pp01, vones, lacc[qt]);
            lacc[qt] = mfma16x16x32h(pp23, vones, lacc[qt]);
        }
        __builtin_amdgcn_s_setprio(0);
    }

    // ---- cross-wave combine; obuf ALIASES the staging LDS ----
    __syncthreads();
    float (*obuf)[3][4][64][4] = (float(*)[3][4][64][4])smem;   // 48KB
    float (*lbuf)[4][16]       = (float(*)[4][16])(smem + 49152);

    #pragma unroll
    for (int qt = 0; qt < 4; ++qt) {
        if (qt != w) {
            int j = qt - (qt > w ? 1 : 0);
            #pragma unroll
            for (int ht = 0; ht < 4; ++ht)
                *(f32x4*)&obuf[w][j][ht][lane][0] = oacc[qt][ht];
        }
    }
    // publish row sums (all cols of lacc identical; lanes with lr==0 write)
    if (lr == 0) {
        #pragma unroll
        for (int qt = 0; qt < 4; ++qt)
            #pragma unroll
            for (int r = 0; r < 4; ++r)
                lbuf[w][qt][lq * 4 + r] = lacc[qt][r];
    }
    __syncthreads();

    // wave w finalizes qt == w
    f32x4 osum[4];
    #pragma unroll
    for (int qt = 0; qt < 4; ++qt)
        if (qt == w) {
            #pragma unroll
            for (int ht = 0; ht < 4; ++ht) osum[ht] = oacc[qt][ht];
        }
    #pragma unroll
    for (int w2 = 0; w2 < 4; ++w2) {
        if (w2 == w) continue;
        int j = w - (w > w2 ? 1 : 0);
        #pragma unroll
        for (int ht = 0; ht < 4; ++ht)
            osum[ht] += *(const f32x4*)&obuf[w2][j][ht][lane][0];
    }
    float linv[4];
    #pragma unroll
    for (int r = 0; r < 4; ++r) {
        int rr = lq * 4 + r;
        linv[r] = 1.0f / (lbuf[0][w][rr] + lbuf[1][w][rr] + lbuf[2][w][rr] + lbuf[3][w][rr]);
    }
    #pragma unroll
    for (int r = 0; r < 4; ++r) {
        int row = q0 + w * 16 + lq * 4 + r;
        #pragma unroll
        for (int ht = 0; ht < 4; ++ht)
            Oout[(size_t)row * DMODEL + h * HDIM + ht * 16 + lr] =
                __float2bfloat16(osum[ht][r] * linv[r]);
    }
}

// ---------------------------------------------------------------------------
extern "C" void kernel_launch(void* const* d_in, const int* in_sizes, int n_in,
                              void* d_out, int out_size, void* d_ws, size_t ws_size,
                              hipStream_t stream) {
    const float* X  = (const float*)d_in[0];
    const float* Wq = (const float*)d_in[1];
    const float* Wk = (const float*)d_in[2];
    const float* Wv = (const float*)d_in[3];
    const float* Wo = (const float*)d_in[4];
    const float* bo = (const float*)d_in[5];
    float* out = (float*)d_out;

    char* ws = (char*)d_ws;
    bf16* Wt = (bf16*)ws;                                  // [4][512][512] bf16
    bf16* Xb = (bf16*)(ws + (size_t)4 * DMODEL * DMODEL * 2);
    bf16* Qm = Xb + (size_t)S_LEN * DMODEL;
    bf16* Km = Qm + (size_t)S_LEN * DMODEL;
    _Float16* Vt = (_Float16*)(Km + (size_t)S_LEN * DMODEL);   // [512][4096] f16 (permuted)
    bf16* AO = (bf16*)(Vt + (size_t)S_LEN * DMODEL);

    bf16* Wot = Wt + (size_t)3 * DMODEL * DMODEL;

    prep<<<2048, 256, 0, stream>>>(X, Wq, Wk, Wv, Wo, Xb, Wt);

    gemm_qkv<<<dim3(S_LEN / 64, DMODEL / 64), 256, 0, stream>>>(
        Xb, Wt, Qm, Km, Vt);

    attn_kernel<<<dim3(NHEADS, S_LEN / 64), 256, 0, stream>>>(Qm, Km, Vt, AO);

    gemm_out<<<dim3(S_LEN / 64, DMODEL / 64), 256, 0, stream>>>(AO, Wot, out, bo);
}